// Round 1
// baseline (712.178 us; speedup 1.0000x reference)
//
#include <hip/hip_runtime.h>
#include <math.h>

#define EPSF 1e-5f

typedef __attribute__((ext_vector_type(4))) int i32x4;

// ---------------------------------------------------------------------------
// async global->LDS, 16B per lane. lds ptr must be the wave-uniform base;
// HW adds lane*16.
__device__ __forceinline__ void gload_lds16(const void* g, void* l) {
  __builtin_amdgcn_global_load_lds(
      (const __attribute__((address_space(1))) void*)g,
      (__attribute__((address_space(3))) void*)l, 16, 0, 0);
}

// ---------------------------------------------------------------------------
__global__ void zero_sums_kernel(double* sums) {
  if (threadIdx.x < 3) sums[threadIdx.x] = 0.0;
}

// ---------------------------------------------------------------------------
// abs-mean reduction over one 16.8M-element matrix per blockIdx.y
__global__ __launch_bounds__(256) void absmean_kernel(
    const float* __restrict__ wg, const float* __restrict__ wu,
    const float* __restrict__ wd, double* __restrict__ sums) {
  const int N4 = 16777216 / 4;
  const float* W = (blockIdx.y == 0) ? wg : ((blockIdx.y == 1) ? wu : wd);
  double acc = 0.0;
  const int stride = gridDim.x * 256;
  for (int i = blockIdx.x * 256 + threadIdx.x; i < N4; i += stride) {
    float4 v = ((const float4*)W)[i];
    acc += (double)fabsf(v.x);
    acc += (double)fabsf(v.y);
    acc += (double)fabsf(v.z);
    acc += (double)fabsf(v.w);
  }
  for (int o = 32; o > 0; o >>= 1) acc += __shfl_down(acc, o);
  __shared__ double sred[4];
  const int wid = threadIdx.x >> 6, lane = threadIdx.x & 63;
  if (lane == 0) sred[wid] = acc;
  __syncthreads();
  if (threadIdx.x == 0)
    atomicAdd(&sums[blockIdx.y], sred[0] + sred[1] + sred[2] + sred[3]);
}

// ---------------------------------------------------------------------------
// ternary quantize: t = clip(round(w/scale), -1, 1) as int8; publish scales
__global__ __launch_bounds__(256) void wquant_kernel(
    const float* __restrict__ wg, const float* __restrict__ wu,
    const float* __restrict__ wd, signed char* __restrict__ qg,
    signed char* __restrict__ qu, signed char* __restrict__ qd,
    const double* __restrict__ sums, float* __restrict__ scalef) {
  const int mat = blockIdx.y;
  const float* W = (mat == 0) ? wg : ((mat == 1) ? wu : wd);
  signed char* Q = (mat == 0) ? qg : ((mat == 1) ? qu : qd);
  // mean in double (N = 2^24, division exact), round once to f32, clip EPS
  const float scale = fmaxf((float)(sums[mat] * (1.0 / 16777216.0)), EPSF);
  if (blockIdx.x == 0 && threadIdx.x == 0) scalef[mat] = scale;
  const int i = blockIdx.x * 256 + threadIdx.x;  // over float4 groups
  float4 v = ((const float4*)W)[i];
  // true IEEE division to match np's w/scale rounding boundaries
  int q0 = (int)fminf(fmaxf(rintf(v.x / scale), -1.f), 1.f);
  int q1 = (int)fminf(fmaxf(rintf(v.y / scale), -1.f), 1.f);
  int q2 = (int)fminf(fmaxf(rintf(v.z / scale), -1.f), 1.f);
  int q3 = (int)fminf(fmaxf(rintf(v.w / scale), -1.f), 1.f);
  int packed = (q0 & 0xff) | ((q1 & 0xff) << 8) | ((q2 & 0xff) << 16) | (q3 << 24);
  ((int*)Q)[i] = packed;
}

// ---------------------------------------------------------------------------
// FWHT along rows of length N (power of 2) + per-row absmax int8 quant.
// Same butterfly pair order as reference => bitwise-identical fp32.
template <int N>
__global__ __launch_bounds__(256) void fwht_quant_kernel(
    const float* __restrict__ X, signed char* __restrict__ Q,
    float* __restrict__ drow, float cnorm) {
  __shared__ float s[N];
  __shared__ float red[4];
  const int tid = threadIdx.x;
  const size_t row = blockIdx.x;
  const float* x = X + row * (size_t)N;
  for (int i = tid; i < N / 4; i += 256)
    ((float4*)s)[i] = ((const float4*)x)[i];
  __syncthreads();
  for (int h = 1; h < N; h <<= 1) {
    for (int p = tid; p < N / 2; p += 256) {
      int i = ((p & ~(h - 1)) << 1) | (p & (h - 1));
      int j = i + h;
      float a = s[i], b = s[j];
      s[i] = a + b;
      s[j] = a - b;
    }
    __syncthreads();
  }
  const int PER = N / 256;
  float m = 0.f;
  for (int i = tid * PER; i < tid * PER + PER; ++i) m = fmaxf(m, fabsf(s[i]));
  for (int o = 32; o > 0; o >>= 1) m = fmaxf(m, __shfl_xor(m, o));
  const int wid = tid >> 6, lane = tid & 63;
  if (lane == 0) red[wid] = m;
  __syncthreads();
  m = fmaxf(fmaxf(red[0], red[1]), fmaxf(red[2], red[3]));
  const float maxv = fmaxf(m * cnorm, EPSF);  // max is monotone under *cnorm
  const float scale = 127.0f / maxv;
  if (tid == 0) drow[row] = maxv / 127.0f;  // dequant = 1/scale (ulp-equal)
  const size_t qbase = row * (size_t)N + (size_t)tid * PER;
#pragma unroll
  for (int i0 = 0; i0 < PER; i0 += 4) {
    int q[4];
#pragma unroll
    for (int k = 0; k < 4; ++k) {
      float y = s[tid * PER + i0 + k] * cnorm;
      float qf = rintf(y * scale);
      qf = fminf(fmaxf(qf, -128.f), 127.f);
      q[k] = (int)qf;
    }
    int packed =
        (q[0] & 0xff) | ((q[1] & 0xff) << 8) | ((q[2] & 0xff) << 16) | (q[3] << 24);
    *(int*)(Q + qbase + i0) = packed;
  }
}

// ---------------------------------------------------------------------------
// GEMM1: h = silu(xq@wgT * sgdr) * (xq@wuT * sudr). A=[4096][2048] i8,
// B=[8192][2048] i8 (both K-major). 128x128 tile, BK=64, 4 waves 2x2,
// each wave 64x64 via 4x4 of mfma_i32_16x16x64_i8. Double-buffered LDS.
__global__ __launch_bounds__(256) void gemm1_kernel(
    const signed char* __restrict__ Aq, const signed char* __restrict__ Bg,
    const signed char* __restrict__ Bu, const float* __restrict__ drow,
    const float* __restrict__ scalef, float* __restrict__ H) {
  const int K = 2048;
  __shared__ __align__(16) signed char sA[2][128 * 64];
  __shared__ __align__(16) signed char sG[2][128 * 64];
  __shared__ __align__(16) signed char sU[2][128 * 64];
  const int tid = threadIdx.x;
  const int wid = tid >> 6;
  const int lane = tid & 63;
  const int wr = wid >> 1, wc = wid & 1;
  const int mbase = blockIdx.y * 128, nbase = blockIdx.x * 128;
  const int srow = tid >> 2;
  const int scol = (tid & 3) << 4;

  const signed char* gA = Aq + (size_t)(mbase + srow) * K + scol;
  const signed char* gG = Bg + (size_t)(nbase + srow) * K + scol;
  const signed char* gU = Bu + (size_t)(nbase + srow) * K + scol;

  i32x4 accG[4][4] = {};
  i32x4 accU[4][4] = {};

  auto stage = [&](int buf, int kk) {
    const size_t o = (size_t)kk;
    const int lb = wid << 10;  // wave-uniform LDS base (lane*16 added by HW)
    gload_lds16(gA + o, &sA[buf][lb]);
    gload_lds16(gA + o + (size_t)64 * K, &sA[buf][4096 + lb]);
    gload_lds16(gG + o, &sG[buf][lb]);
    gload_lds16(gG + o + (size_t)64 * K, &sG[buf][4096 + lb]);
    gload_lds16(gU + o, &sU[buf][lb]);
    gload_lds16(gU + o + (size_t)64 * K, &sU[buf][4096 + lb]);
  };

  stage(0, 0);
  __syncthreads();
  int cur = 0;
  const int ko = (lane >> 4) << 4;
  const int rA = (wr << 6) + (lane & 15);
  const int rB = (wc << 6) + (lane & 15);
  for (int t = 0; t < K / 64; ++t) {
    if (t + 1 < K / 64) stage(cur ^ 1, (t + 1) * 64);
    i32x4 a[4], bg[4], bu[4];
#pragma unroll
    for (int m = 0; m < 4; ++m)
      a[m] = *(const i32x4*)&sA[cur][(rA + m * 16) * 64 + ko];
#pragma unroll
    for (int n = 0; n < 4; ++n) {
      bg[n] = *(const i32x4*)&sG[cur][(rB + n * 16) * 64 + ko];
      bu[n] = *(const i32x4*)&sU[cur][(rB + n * 16) * 64 + ko];
    }
#pragma unroll
    for (int m = 0; m < 4; ++m)
#pragma unroll
      for (int n = 0; n < 4; ++n) {
        accG[m][n] =
            __builtin_amdgcn_mfma_i32_16x16x64_i8(a[m], bg[n], accG[m][n], 0, 0, 0);
        accU[m][n] =
            __builtin_amdgcn_mfma_i32_16x16x64_i8(a[m], bu[n], accU[m][n], 0, 0, 0);
      }
    __syncthreads();
    cur ^= 1;
  }

  const float sg = scalef[0], su = scalef[1];
  const int orow = (lane >> 4) << 2;  // C/D: col=lane&15, row=(lane>>4)*4+j
  const int ocol = lane & 15;
#pragma unroll
  for (int m = 0; m < 4; ++m)
#pragma unroll
    for (int n = 0; n < 4; ++n)
#pragma unroll
      for (int j = 0; j < 4; ++j) {
        int grow = mbase + (wr << 6) + m * 16 + orow + j;
        int gcol = nbase + (wc << 6) + n * 16 + ocol;
        float dr = drow[grow];
        float gate = (float)accG[m][n][j] * (sg * dr);
        float up = (float)accU[m][n][j] * (su * dr);
        float hval = (gate / (1.0f + expf(-gate))) * up;
        H[(size_t)grow * 8192 + gcol] = hval;
      }
}

// ---------------------------------------------------------------------------
// GEMM2: out = (hq@wdT) * sd * dr2.  A=[4096][8192] i8, B=[2048][8192] i8.
__global__ __launch_bounds__(256) void gemm2_kernel(
    const signed char* __restrict__ Aq, const signed char* __restrict__ Bq,
    const float* __restrict__ drow, const float* __restrict__ scalef,
    float* __restrict__ O) {
  const int K = 8192;
  __shared__ __align__(16) signed char sA[2][128 * 64];
  __shared__ __align__(16) signed char sB[2][128 * 64];
  const int tid = threadIdx.x;
  const int wid = tid >> 6;
  const int lane = tid & 63;
  const int wr = wid >> 1, wc = wid & 1;
  const int mbase = blockIdx.y * 128, nbase = blockIdx.x * 128;
  const int srow = tid >> 2;
  const int scol = (tid & 3) << 4;

  const signed char* gA = Aq + (size_t)(mbase + srow) * K + scol;
  const signed char* gB = Bq + (size_t)(nbase + srow) * K + scol;

  i32x4 acc[4][4] = {};

  auto stage = [&](int buf, int kk) {
    const size_t o = (size_t)kk;
    const int lb = wid << 10;
    gload_lds16(gA + o, &sA[buf][lb]);
    gload_lds16(gA + o + (size_t)64 * K, &sA[buf][4096 + lb]);
    gload_lds16(gB + o, &sB[buf][lb]);
    gload_lds16(gB + o + (size_t)64 * K, &sB[buf][4096 + lb]);
  };

  stage(0, 0);
  __syncthreads();
  int cur = 0;
  const int ko = (lane >> 4) << 4;
  const int rA = (wr << 6) + (lane & 15);
  const int rB = (wc << 6) + (lane & 15);
  for (int t = 0; t < K / 64; ++t) {
    if (t + 1 < K / 64) stage(cur ^ 1, (t + 1) * 64);
    i32x4 a[4], b[4];
#pragma unroll
    for (int m = 0; m < 4; ++m)
      a[m] = *(const i32x4*)&sA[cur][(rA + m * 16) * 64 + ko];
#pragma unroll
    for (int n = 0; n < 4; ++n)
      b[n] = *(const i32x4*)&sB[cur][(rB + n * 16) * 64 + ko];
#pragma unroll
    for (int m = 0; m < 4; ++m)
#pragma unroll
      for (int n = 0; n < 4; ++n)
        acc[m][n] = __builtin_amdgcn_mfma_i32_16x16x64_i8(a[m], b[n], acc[m][n], 0, 0, 0);
    __syncthreads();
    cur ^= 1;
  }

  const float sd = scalef[2];
  const int orow = (lane >> 4) << 2;
  const int ocol = lane & 15;
#pragma unroll
  for (int m = 0; m < 4; ++m)
#pragma unroll
    for (int n = 0; n < 4; ++n)
#pragma unroll
      for (int j = 0; j < 4; ++j) {
        int grow = mbase + (wr << 6) + m * 16 + orow + j;
        int gcol = nbase + (wc << 6) + n * 16 + ocol;
        O[(size_t)grow * 2048 + gcol] = (float)acc[m][n][j] * (sd * drow[grow]);
      }
}

// ---------------------------------------------------------------------------
extern "C" void kernel_launch(void* const* d_in, const int* in_sizes, int n_in,
                              void* d_out, int out_size, void* d_ws, size_t ws_size,
                              hipStream_t stream) {
  (void)in_sizes; (void)n_in; (void)out_size; (void)ws_size;
  const float* x = (const float*)d_in[0];
  const float* wg = (const float*)d_in[1];
  const float* wu = (const float*)d_in[2];
  const float* wd = (const float*)d_in[3];
  float* out = (float*)d_out;

  // workspace layout (~216 MiB)
  char* ws = (char*)d_ws;
  double* sums = (double*)ws;                    // 24 B
  float* scalef = (float*)(ws + 256);            // 12 B
  size_t off = 1024;
  signed char* qg = (signed char*)(ws + off); off += 16777216;   // 8192x2048
  signed char* qu = (signed char*)(ws + off); off += 16777216;
  signed char* qd = (signed char*)(ws + off); off += 16777216;   // 2048x8192
  signed char* xq = (signed char*)(ws + off); off += 8388608;    // 4096x2048
  signed char* hq = (signed char*)(ws + off); off += 33554432;   // 4096x8192
  float* dr1 = (float*)(ws + off); off += 16384;                 // 4096
  float* dr2 = (float*)(ws + off); off += 16384;                 // 4096
  float* Hbuf = (float*)(ws + off); off += (size_t)4096 * 8192 * 4;  // fp32 h

  zero_sums_kernel<<<1, 64, 0, stream>>>(sums);
  absmean_kernel<<<dim3(1024, 3), 256, 0, stream>>>(wg, wu, wd, sums);
  wquant_kernel<<<dim3(16384, 3), 256, 0, stream>>>(wg, wu, wd, qg, qu, qd, sums,
                                                    scalef);
  const float c1 = (float)(1.0 / sqrt(2048.0));
  const float c2 = (float)(1.0 / sqrt(8192.0));
  fwht_quant_kernel<2048><<<4096, 256, 0, stream>>>(x, xq, dr1, c1);
  gemm1_kernel<<<dim3(64, 32), 256, 0, stream>>>(xq, qg, qu, dr1, scalef, Hbuf);
  fwht_quant_kernel<8192><<<4096, 256, 0, stream>>>(Hbuf, hq, dr2, c2);
  gemm2_kernel<<<dim3(16, 32), 256, 0, stream>>>(hq, qd, dr2, scalef, out);
}

// Round 2
// 630.644 us; speedup vs baseline: 1.1293x; 1.1293x over previous
//
#include <hip/hip_runtime.h>
#include <math.h>

#define EPSF 1e-5f

typedef __attribute__((ext_vector_type(4))) int i32x4;

#define S_WAITCNT_VMCNT(N) asm volatile("s_waitcnt vmcnt(" #N ")" ::: "memory")
#define S_WAITCNT_LGKM0() asm volatile("s_waitcnt lgkmcnt(0)" ::: "memory")

// async global->LDS, 16B per lane. lds ptr must be the wave-uniform base;
// HW adds lane*16.
__device__ __forceinline__ void gload_lds16(const void* g, void* l) {
  __builtin_amdgcn_global_load_lds(
      (const __attribute__((address_space(1))) void*)g,
      (__attribute__((address_space(3))) void*)l, 16, 0, 0);
}

// ---------------------------------------------------------------------------
__global__ void zero_sums_kernel(double* sums) {
  if (threadIdx.x < 3) sums[threadIdx.x] = 0.0;
}

// ---------------------------------------------------------------------------
__global__ __launch_bounds__(256) void absmean_kernel(
    const float* __restrict__ wg, const float* __restrict__ wu,
    const float* __restrict__ wd, double* __restrict__ sums) {
  const int N4 = 16777216 / 4;
  const float* W = (blockIdx.y == 0) ? wg : ((blockIdx.y == 1) ? wu : wd);
  double acc = 0.0;
  const int stride = gridDim.x * 256;
  for (int i = blockIdx.x * 256 + threadIdx.x; i < N4; i += stride) {
    float4 v = ((const float4*)W)[i];
    acc += (double)fabsf(v.x);
    acc += (double)fabsf(v.y);
    acc += (double)fabsf(v.z);
    acc += (double)fabsf(v.w);
  }
  for (int o = 32; o > 0; o >>= 1) acc += __shfl_down(acc, o);
  __shared__ double sred[4];
  const int wid = threadIdx.x >> 6, lane = threadIdx.x & 63;
  if (lane == 0) sred[wid] = acc;
  __syncthreads();
  if (threadIdx.x == 0)
    atomicAdd(&sums[blockIdx.y], sred[0] + sred[1] + sred[2] + sred[3]);
}

// ---------------------------------------------------------------------------
__global__ __launch_bounds__(256) void wquant_kernel(
    const float* __restrict__ wg, const float* __restrict__ wu,
    const float* __restrict__ wd, signed char* __restrict__ qg,
    signed char* __restrict__ qu, signed char* __restrict__ qd,
    const double* __restrict__ sums, float* __restrict__ scalef) {
  const int mat = blockIdx.y;
  const float* W = (mat == 0) ? wg : ((mat == 1) ? wu : wd);
  signed char* Q = (mat == 0) ? qg : ((mat == 1) ? qu : qd);
  const float scale = fmaxf((float)(sums[mat] * (1.0 / 16777216.0)), EPSF);
  if (blockIdx.x == 0 && threadIdx.x == 0) scalef[mat] = scale;
  const int i = blockIdx.x * 256 + threadIdx.x;
  float4 v = ((const float4*)W)[i];
  int q0 = (int)fminf(fmaxf(rintf(v.x / scale), -1.f), 1.f);
  int q1 = (int)fminf(fmaxf(rintf(v.y / scale), -1.f), 1.f);
  int q2 = (int)fminf(fmaxf(rintf(v.z / scale), -1.f), 1.f);
  int q3 = (int)fminf(fmaxf(rintf(v.w / scale), -1.f), 1.f);
  int packed = (q0 & 0xff) | ((q1 & 0xff) << 8) | ((q2 & 0xff) << 16) | (q3 << 24);
  ((int*)Q)[i] = packed;
}

// ---------------------------------------------------------------------------
// FWHT rows of length N + per-row absmax int8 quant; reference pair order.
template <int N>
__global__ __launch_bounds__(256) void fwht_quant_kernel(
    const float* __restrict__ X, signed char* __restrict__ Q,
    float* __restrict__ drow, float cnorm) {
  __shared__ float s[N];
  __shared__ float red[4];
  const int tid = threadIdx.x;
  const size_t row = blockIdx.x;
  const float* x = X + row * (size_t)N;
  for (int i = tid; i < N / 4; i += 256)
    ((float4*)s)[i] = ((const float4*)x)[i];
  __syncthreads();
  for (int h = 1; h < N; h <<= 1) {
    for (int p = tid; p < N / 2; p += 256) {
      int i = ((p & ~(h - 1)) << 1) | (p & (h - 1));
      int j = i + h;
      float a = s[i], b = s[j];
      s[i] = a + b;
      s[j] = a - b;
    }
    __syncthreads();
  }
  const int PER = N / 256;
  float m = 0.f;
  for (int i = tid * PER; i < tid * PER + PER; ++i) m = fmaxf(m, fabsf(s[i]));
  for (int o = 32; o > 0; o >>= 1) m = fmaxf(m, __shfl_xor(m, o));
  const int wid = tid >> 6, lane = tid & 63;
  if (lane == 0) red[wid] = m;
  __syncthreads();
  m = fmaxf(fmaxf(red[0], red[1]), fmaxf(red[2], red[3]));
  const float maxv = fmaxf(m * cnorm, EPSF);
  const float scale = 127.0f / maxv;
  if (tid == 0) drow[row] = maxv / 127.0f;
  const size_t qbase = row * (size_t)N + (size_t)tid * PER;
#pragma unroll
  for (int i0 = 0; i0 < PER; i0 += 4) {
    int q[4];
#pragma unroll
    for (int k = 0; k < 4; ++k) {
      float y = s[tid * PER + i0 + k] * cnorm;
      float qf = rintf(y * scale);
      qf = fminf(fmaxf(qf, -128.f), 127.f);
      q[k] = (int)qf;
    }
    int packed =
        (q[0] & 0xff) | ((q[1] & 0xff) << 8) | ((q[2] & 0xff) << 16) | (q[3] << 24);
    *(int*)(Q + qbase + i0) = packed;
  }
}

// ---------------------------------------------------------------------------
// GEMM1: h = silu(xq@wgT * sg*dr) * (xq@wuT * su*dr).
// 128x128 tile, BK=64, 4 waves 2x2, 3-buffer counted-vmcnt pipeline,
// T2 XOR swizzle (pre-swizzled global source, swizzled ds_read), T1 XCD swz.
__global__ __launch_bounds__(256, 2) void gemm1_kernel(
    const signed char* __restrict__ Aq, const signed char* __restrict__ Bg,
    const signed char* __restrict__ Bu, const float* __restrict__ drow,
    const float* __restrict__ scalef, float* __restrict__ H) {
  const int K = 2048, T = K / 64;
  const int BUF = 24576;  // A 8K | G 8K | U 8K
  __shared__ __align__(16) signed char smem[3 * BUF];  // 72 KiB
  const int tid = threadIdx.x;
  const int wid = tid >> 6;
  const int lane = tid & 63;
  const int wr = wid >> 1, wc = wid & 1;

  // T1: grid 64x32 = 2048 blocks, %8==0 -> contiguous chunk per XCD
  const int orig = blockIdx.y * 64 + blockIdx.x;
  const int swz = (orig & 7) * 256 + (orig >> 3);
  const int mbase = (swz >> 6) * 128, nbase = (swz & 63) * 128;

  const int srow = tid >> 2;
  const int scol = (((tid & 3) ^ ((srow >> 1) & 3)) << 4);  // T2 pre-swizzle
  const signed char* gA = Aq + (size_t)(mbase + srow) * K + scol;
  const signed char* gG = Bg + (size_t)(nbase + srow) * K + scol;
  const signed char* gU = Bu + (size_t)(nbase + srow) * K + scol;

  i32x4 accG[4][4] = {};
  i32x4 accU[4][4] = {};

  auto stage = [&](int boff, int kk) {
    const size_t o = (size_t)kk;
    const int lb = boff + (wid << 10);
    gload_lds16(gA + o, &smem[lb]);
    gload_lds16(gA + o + (size_t)64 * K, &smem[lb + 4096]);
    gload_lds16(gG + o, &smem[lb + 8192]);
    gload_lds16(gG + o + (size_t)64 * K, &smem[lb + 12288]);
    gload_lds16(gU + o, &smem[lb + 16384]);
    gload_lds16(gU + o + (size_t)64 * K, &smem[lb + 20480]);
  };

  // T2 read swizzle: word slot = kw ^ ((row>>1)&3); row = (wr|wc)*64+m*16+(lane&15)
  // -> swizzle term depends only on lane, constant across m/n/matrix.
  const int kos = (((lane >> 4) ^ ((lane >> 1) & 3)) << 4);
  const int rA = (wr << 6) + (lane & 15);
  const int rB = (wc << 6) + (lane & 15);

  stage(0, 0);
  stage(BUF, 64);
  int bc = 0, bn = BUF, bf = 2 * BUF;
  for (int t = 0; t < T; ++t) {
    S_WAITCNT_VMCNT(6);                 // tile t landed (tile t+1 in flight)
    __builtin_amdgcn_s_barrier();       // all waves' portions visible
    __builtin_amdgcn_sched_barrier(0);
    const int kk = (t + 2 < T) ? (t + 2) * 64 : (T - 1) * 64;
    stage(bf, kk);                      // free buffer; uniform 6 loads/iter
    i32x4 a[4], bg[4], bu[4];
#pragma unroll
    for (int m = 0; m < 4; ++m)
      a[m] = *(const i32x4*)&smem[bc + (rA + m * 16) * 64 + kos];
#pragma unroll
    for (int n = 0; n < 4; ++n) {
      bg[n] = *(const i32x4*)&smem[bc + 8192 + (rB + n * 16) * 64 + kos];
      bu[n] = *(const i32x4*)&smem[bc + 16384 + (rB + n * 16) * 64 + kos];
    }
    __builtin_amdgcn_s_setprio(1);
#pragma unroll
    for (int m = 0; m < 4; ++m)
#pragma unroll
      for (int n = 0; n < 4; ++n) {
        accG[m][n] =
            __builtin_amdgcn_mfma_i32_16x16x64_i8(a[m], bg[n], accG[m][n], 0, 0, 0);
        accU[m][n] =
            __builtin_amdgcn_mfma_i32_16x16x64_i8(a[m], bu[n], accU[m][n], 0, 0, 0);
      }
    __builtin_amdgcn_s_setprio(0);
    S_WAITCNT_LGKM0();                  // my reads of bc done (buffer reuse safety)
    __builtin_amdgcn_sched_barrier(0);
    const int tmp = bc; bc = bn; bn = bf; bf = tmp;
  }

  const float sg = scalef[0], su = scalef[1];
  const int orow = (lane >> 4) << 2;  // C/D: col=lane&15, row=(lane>>4)*4+j
  const int ocol = lane & 15;
#pragma unroll
  for (int m = 0; m < 4; ++m)
#pragma unroll
    for (int n = 0; n < 4; ++n)
#pragma unroll
      for (int j = 0; j < 4; ++j) {
        int grow = mbase + (wr << 6) + m * 16 + orow + j;
        int gcol = nbase + (wc << 6) + n * 16 + ocol;
        float dr = drow[grow];
        float gate = (float)accG[m][n][j] * (sg * dr);
        float up = (float)accU[m][n][j] * (su * dr);
        float hval = (gate / (1.0f + expf(-gate))) * up;
        H[(size_t)grow * 8192 + gcol] = hval;
      }
}

// ---------------------------------------------------------------------------
// GEMM2: out = (hq@wdT) * sd * dr2. Same pipeline, single B.
__global__ __launch_bounds__(256, 3) void gemm2_kernel(
    const signed char* __restrict__ Aq, const signed char* __restrict__ Bq,
    const float* __restrict__ drow, const float* __restrict__ scalef,
    float* __restrict__ O) {
  const int K = 8192, T = K / 64;
  const int BUF = 16384;  // A 8K | B 8K
  __shared__ __align__(16) signed char smem[3 * BUF];  // 48 KiB
  const int tid = threadIdx.x;
  const int wid = tid >> 6;
  const int lane = tid & 63;
  const int wr = wid >> 1, wc = wid & 1;

  // T1: grid 16x32 = 512 blocks
  const int orig = blockIdx.y * 16 + blockIdx.x;
  const int swz = (orig & 7) * 64 + (orig >> 3);
  const int mbase = (swz >> 4) * 128, nbase = (swz & 15) * 128;

  const int srow = tid >> 2;
  const int scol = (((tid & 3) ^ ((srow >> 1) & 3)) << 4);
  const signed char* gA = Aq + (size_t)(mbase + srow) * K + scol;
  const signed char* gB = Bq + (size_t)(nbase + srow) * K + scol;

  i32x4 acc[4][4] = {};

  auto stage = [&](int boff, int kk) {
    const size_t o = (size_t)kk;
    const int lb = boff + (wid << 10);
    gload_lds16(gA + o, &smem[lb]);
    gload_lds16(gA + o + (size_t)64 * K, &smem[lb + 4096]);
    gload_lds16(gB + o, &smem[lb + 8192]);
    gload_lds16(gB + o + (size_t)64 * K, &smem[lb + 12288]);
  };

  const int kos = (((lane >> 4) ^ ((lane >> 1) & 3)) << 4);
  const int rA = (wr << 6) + (lane & 15);
  const int rB = (wc << 6) + (lane & 15);

  stage(0, 0);
  stage(BUF, 64);
  int bc = 0, bn = BUF, bf = 2 * BUF;
  for (int t = 0; t < T; ++t) {
    S_WAITCNT_VMCNT(4);
    __builtin_amdgcn_s_barrier();
    __builtin_amdgcn_sched_barrier(0);
    const int kk = (t + 2 < T) ? (t + 2) * 64 : (T - 1) * 64;
    stage(bf, kk);
    i32x4 a[4], b[4];
#pragma unroll
    for (int m = 0; m < 4; ++m)
      a[m] = *(const i32x4*)&smem[bc + (rA + m * 16) * 64 + kos];
#pragma unroll
    for (int n = 0; n < 4; ++n)
      b[n] = *(const i32x4*)&smem[bc + 8192 + (rB + n * 16) * 64 + kos];
    __builtin_amdgcn_s_setprio(1);
#pragma unroll
    for (int m = 0; m < 4; ++m)
#pragma unroll
      for (int n = 0; n < 4; ++n)
        acc[m][n] = __builtin_amdgcn_mfma_i32_16x16x64_i8(a[m], b[n], acc[m][n], 0, 0, 0);
    __builtin_amdgcn_s_setprio(0);
    S_WAITCNT_LGKM0();
    __builtin_amdgcn_sched_barrier(0);
    const int tmp = bc; bc = bn; bn = bf; bf = tmp;
  }

  const float sd = scalef[2];
  const int orow = (lane >> 4) << 2;
  const int ocol = lane & 15;
#pragma unroll
  for (int m = 0; m < 4; ++m)
#pragma unroll
    for (int n = 0; n < 4; ++n)
#pragma unroll
      for (int j = 0; j < 4; ++j) {
        int grow = mbase + (wr << 6) + m * 16 + orow + j;
        int gcol = nbase + (wc << 6) + n * 16 + ocol;
        O[(size_t)grow * 2048 + gcol] = (float)acc[m][n][j] * (sd * drow[grow]);
      }
}

// ---------------------------------------------------------------------------
extern "C" void kernel_launch(void* const* d_in, const int* in_sizes, int n_in,
                              void* d_out, int out_size, void* d_ws, size_t ws_size,
                              hipStream_t stream) {
  (void)in_sizes; (void)n_in; (void)out_size; (void)ws_size;
  const float* x = (const float*)d_in[0];
  const float* wg = (const float*)d_in[1];
  const float* wu = (const float*)d_in[2];
  const float* wd = (const float*)d_in[3];
  float* out = (float*)d_out;

  char* ws = (char*)d_ws;
  double* sums = (double*)ws;
  float* scalef = (float*)(ws + 256);
  size_t off = 1024;
  signed char* qg = (signed char*)(ws + off); off += 16777216;
  signed char* qu = (signed char*)(ws + off); off += 16777216;
  signed char* qd = (signed char*)(ws + off); off += 16777216;
  signed char* xq = (signed char*)(ws + off); off += 8388608;
  signed char* hq = (signed char*)(ws + off); off += 33554432;
  float* dr1 = (float*)(ws + off); off += 16384;
  float* dr2 = (float*)(ws + off); off += 16384;
  float* Hbuf = (float*)(ws + off); off += (size_t)4096 * 8192 * 4;

  zero_sums_kernel<<<1, 64, 0, stream>>>(sums);
  absmean_kernel<<<dim3(1024, 3), 256, 0, stream>>>(wg, wu, wd, sums);
  wquant_kernel<<<dim3(16384, 3), 256, 0, stream>>>(wg, wu, wd, qg, qu, qd, sums,
                                                    scalef);
  const float c1 = (float)(1.0 / sqrt(2048.0));
  const float c2 = (float)(1.0 / sqrt(8192.0));
  fwht_quant_kernel<2048><<<4096, 256, 0, stream>>>(x, xq, dr1, c1);
  gemm1_kernel<<<dim3(64, 32), 256, 0, stream>>>(xq, qg, qu, dr1, scalef, Hbuf);
  fwht_quant_kernel<8192><<<4096, 256, 0, stream>>>(Hbuf, hq, dr2, c2);
  gemm2_kernel<<<dim3(16, 32), 256, 0, stream>>>(hq, qd, dr2, scalef, out);
}

// Round 3
// 610.808 us; speedup vs baseline: 1.1660x; 1.0325x over previous
//
#include <hip/hip_runtime.h>
#include <math.h>

#define EPSF 1e-5f

typedef __attribute__((ext_vector_type(4))) int i32x4;

#define S_WAITCNT_VMCNT(N) asm volatile("s_waitcnt vmcnt(" #N ")" ::: "memory")
#define S_WAITCNT_LGKM0() asm volatile("s_waitcnt lgkmcnt(0)" ::: "memory")

// async global->LDS, 16B per lane. lds ptr = wave-uniform base; HW adds lane*16.
__device__ __forceinline__ void gload_lds16(const void* g, void* l) {
  __builtin_amdgcn_global_load_lds(
      (const __attribute__((address_space(1))) void*)g,
      (__attribute__((address_space(3))) void*)l, 16, 0, 0);
}

// ---------------------------------------------------------------------------
__global__ void zero_sums_kernel(double* sums) {
  if (threadIdx.x < 3) sums[threadIdx.x] = 0.0;
}

// ---------------------------------------------------------------------------
__global__ __launch_bounds__(256) void absmean_kernel(
    const float* __restrict__ wg, const float* __restrict__ wu,
    const float* __restrict__ wd, double* __restrict__ sums) {
  const int N4 = 16777216 / 4;
  const float* W = (blockIdx.y == 0) ? wg : ((blockIdx.y == 1) ? wu : wd);
  double acc = 0.0;
  const int stride = gridDim.x * 256;
  for (int i = blockIdx.x * 256 + threadIdx.x; i < N4; i += stride) {
    float4 v = ((const float4*)W)[i];
    acc += (double)fabsf(v.x);
    acc += (double)fabsf(v.y);
    acc += (double)fabsf(v.z);
    acc += (double)fabsf(v.w);
  }
  for (int o = 32; o > 0; o >>= 1) acc += __shfl_down(acc, o);
  __shared__ double sred[4];
  const int wid = threadIdx.x >> 6, lane = threadIdx.x & 63;
  if (lane == 0) sred[wid] = acc;
  __syncthreads();
  if (threadIdx.x == 0)
    atomicAdd(&sums[blockIdx.y], sred[0] + sred[1] + sred[2] + sred[3]);
}

// ---------------------------------------------------------------------------
__global__ __launch_bounds__(256) void wquant_kernel(
    const float* __restrict__ wg, const float* __restrict__ wu,
    const float* __restrict__ wd, signed char* __restrict__ qg,
    signed char* __restrict__ qu, signed char* __restrict__ qd,
    const double* __restrict__ sums, float* __restrict__ scalef) {
  const int mat = blockIdx.y;
  const float* W = (mat == 0) ? wg : ((mat == 1) ? wu : wd);
  signed char* Q = (mat == 0) ? qg : ((mat == 1) ? qu : qd);
  const float scale = fmaxf((float)(sums[mat] * (1.0 / 16777216.0)), EPSF);
  if (blockIdx.x == 0 && threadIdx.x == 0) scalef[mat] = scale;
  const int i = blockIdx.x * 256 + threadIdx.x;
  float4 v = ((const float4*)W)[i];
  int q0 = (int)fminf(fmaxf(rintf(v.x / scale), -1.f), 1.f);
  int q1 = (int)fminf(fmaxf(rintf(v.y / scale), -1.f), 1.f);
  int q2 = (int)fminf(fmaxf(rintf(v.z / scale), -1.f), 1.f);
  int q3 = (int)fminf(fmaxf(rintf(v.w / scale), -1.f), 1.f);
  int packed = (q0 & 0xff) | ((q1 & 0xff) << 8) | ((q2 & 0xff) << 16) | (q3 << 24);
  ((int*)Q)[i] = packed;
}

// ---------------------------------------------------------------------------
// FWHT rows of length N + per-row absmax int8 quant; reference pair order.
template <int N>
__global__ __launch_bounds__(256) void fwht_quant_kernel(
    const float* __restrict__ X, signed char* __restrict__ Q,
    float* __restrict__ drow, float cnorm) {
  __shared__ float s[N];
  __shared__ float red[4];
  const int tid = threadIdx.x;
  const size_t row = blockIdx.x;
  const float* x = X + row * (size_t)N;
  for (int i = tid; i < N / 4; i += 256)
    ((float4*)s)[i] = ((const float4*)x)[i];
  __syncthreads();
  for (int h = 1; h < N; h <<= 1) {
    for (int p = tid; p < N / 2; p += 256) {
      int i = ((p & ~(h - 1)) << 1) | (p & (h - 1));
      int j = i + h;
      float a = s[i], b = s[j];
      s[i] = a + b;
      s[j] = a - b;
    }
    __syncthreads();
  }
  const int PER = N / 256;
  float m = 0.f;
  for (int i = tid * PER; i < tid * PER + PER; ++i) m = fmaxf(m, fabsf(s[i]));
  for (int o = 32; o > 0; o >>= 1) m = fmaxf(m, __shfl_xor(m, o));
  const int wid = tid >> 6, lane = tid & 63;
  if (lane == 0) red[wid] = m;
  __syncthreads();
  m = fmaxf(fmaxf(red[0], red[1]), fmaxf(red[2], red[3]));
  const float maxv = fmaxf(m * cnorm, EPSF);
  const float scale = 127.0f / maxv;
  if (tid == 0) drow[row] = maxv / 127.0f;
  const size_t qbase = row * (size_t)N + (size_t)tid * PER;
#pragma unroll
  for (int i0 = 0; i0 < PER; i0 += 4) {
    int q[4];
#pragma unroll
    for (int k = 0; k < 4; ++k) {
      float y = s[tid * PER + i0 + k] * cnorm;
      float qf = rintf(y * scale);
      qf = fminf(fmaxf(qf, -128.f), 127.f);
      q[k] = (int)qf;
    }
    int packed =
        (q[0] & 0xff) | ((q[1] & 0xff) << 8) | ((q[2] & 0xff) << 16) | (q[3] << 24);
    *(int*)(Q + qbase + i0) = packed;
  }
}

// ---------------------------------------------------------------------------
// GEMM1: h = silu(xq@wgT * sg*dr) * (xq@wuT * su*dr).
// BM=256, BN=128, BK=64, 512 thr (8 waves 2M x 4N), per-wave 128x32 dual-mat.
// 3-buffer, counted vmcnt(4), 2 phases/K-tile {G-MFMA | U-MFMA}, T2 swizzle.
__global__ __launch_bounds__(512, 2) void gemm1_kernel(
    const signed char* __restrict__ Aq, const signed char* __restrict__ Bg,
    const signed char* __restrict__ Bu, const float* __restrict__ drow,
    const float* __restrict__ scalef, float* __restrict__ H) {
  const int K = 2048, T = K / 64;
  const int BUF = 32768;  // A 16K | G 8K | U 8K
  __shared__ __align__(16) signed char smem[3 * BUF];  // 96 KiB
  const int tid = threadIdx.x;
  const int wid = tid >> 6;
  const int lane = tid & 63;
  const int wr = wid >> 2, wn = wid & 3;  // 2M x 4N waves

  // XCD-compact region: 1024 blocks; XCD x owns N-cols [8x, 8x+8), all 16 M.
  const int id = blockIdx.x;
  const int xcd = id & 7, j = id >> 3;
  const int mbase = (j & 15) * 256;
  const int nbase = (xcd * 8 + (j >> 4)) * 128;

  const int srow = tid >> 2;                                // 0..127
  const int scol = (((tid & 3) ^ ((srow >> 1) & 3)) << 4);  // T2 pre-swizzle
  const signed char* pA = Aq + (size_t)(mbase + srow) * K + scol;
  const signed char* pG = Bg + (size_t)(nbase + srow) * K + scol;
  const signed char* pU = Bu + (size_t)(nbase + srow) * K + scol;

  i32x4 accG[8][2] = {};
  i32x4 accU[8][2] = {};

  // read swizzle term: constant across fragment index (rows differ by mult of 4)
  const int kos = (((lane >> 4) ^ ((lane >> 1) & 3)) << 4);
  const int rA = (wr << 7) + (lane & 15);  // A local row base
  const int rB = (wn << 5) + (lane & 15);  // B local row base

  const int wb = wid << 10;  // wave staging slice

  // prologue: stage kt0, kt1 (4 gloads each)
  {
    gload_lds16(pA, &smem[wb]);
    gload_lds16(pA + (size_t)128 * K, &smem[8192 + wb]);
    gload_lds16(pG, &smem[16384 + wb]);
    gload_lds16(pU, &smem[24576 + wb]);
    gload_lds16(pA + 64, &smem[BUF + wb]);
    gload_lds16(pA + (size_t)128 * K + 64, &smem[BUF + 8192 + wb]);
    gload_lds16(pG + 64, &smem[BUF + 16384 + wb]);
    gload_lds16(pU + 64, &smem[BUF + 24576 + wb]);
  }

  int bc = 0, bn = BUF, bf = 2 * BUF;
  for (int t = 0; t < T; ++t) {
    const size_t kk = (size_t)((t + 2 < T) ? (t + 2) * 64 : (T - 1) * 64);
    S_WAITCNT_VMCNT(4);            // ktile t landed (t+1's 4 may be in flight)
    __builtin_amdgcn_s_barrier();  // all waves' portions visible
    __builtin_amdgcn_sched_barrier(0);
    // ---- phase 0: read a[0..7], bg[0..1]; stage A rounds of kt t+2
    i32x4 a[8], bg[2], bu[2];
#pragma unroll
    for (int m = 0; m < 8; ++m)
      a[m] = *(const i32x4*)&smem[bc + (rA + m * 16) * 64 + kos];
#pragma unroll
    for (int n = 0; n < 2; ++n)
      bg[n] = *(const i32x4*)&smem[bc + 16384 + (rB + n * 16) * 64 + kos];
    gload_lds16(pA + kk, &smem[bf + wb]);
    gload_lds16(pA + (size_t)128 * K + kk, &smem[bf + 8192 + wb]);
    __builtin_amdgcn_s_barrier();
    S_WAITCNT_LGKM0();
    __builtin_amdgcn_sched_barrier(0);
    __builtin_amdgcn_s_setprio(1);
#pragma unroll
    for (int m = 0; m < 8; ++m)
#pragma unroll
      for (int n = 0; n < 2; ++n)
        accG[m][n] =
            __builtin_amdgcn_mfma_i32_16x16x64_i8(a[m], bg[n], accG[m][n], 0, 0, 0);
    __builtin_amdgcn_s_setprio(0);
    // ---- phase 1: read bu[0..1]; stage G,U rounds of kt t+2
#pragma unroll
    for (int n = 0; n < 2; ++n)
      bu[n] = *(const i32x4*)&smem[bc + 24576 + (rB + n * 16) * 64 + kos];
    gload_lds16(pG + kk, &smem[bf + 16384 + wb]);
    gload_lds16(pU + kk, &smem[bf + 24576 + wb]);
    __builtin_amdgcn_s_barrier();
    S_WAITCNT_LGKM0();
    __builtin_amdgcn_sched_barrier(0);
    __builtin_amdgcn_s_setprio(1);
#pragma unroll
    for (int m = 0; m < 8; ++m)
#pragma unroll
      for (int n = 0; n < 2; ++n)
        accU[m][n] =
            __builtin_amdgcn_mfma_i32_16x16x64_i8(a[m], bu[n], accU[m][n], 0, 0, 0);
    __builtin_amdgcn_s_setprio(0);
    const int tmp = bc; bc = bn; bn = bf; bf = tmp;
  }

  const float sg = scalef[0], su = scalef[1];
  const int orow = (lane >> 4) << 2;  // C/D: col=lane&15, row=(lane>>4)*4+j
  const int ocol = lane & 15;
#pragma unroll
  for (int m = 0; m < 8; ++m)
#pragma unroll
    for (int n = 0; n < 2; ++n)
#pragma unroll
      for (int jj = 0; jj < 4; ++jj) {
        int grow = mbase + (wr << 7) + m * 16 + orow + jj;
        int gcol = nbase + (wn << 5) + n * 16 + ocol;
        float dr = drow[grow];
        float gate = (float)accG[m][n][jj] * (sg * dr);
        float up = (float)accU[m][n][jj] * (su * dr);
        float hval = (gate / (1.0f + expf(-gate))) * up;
        H[(size_t)grow * 8192 + gcol] = hval;
      }
}

// ---------------------------------------------------------------------------
// GEMM2: out = (hq@wdT) * sd * dr2. BM=256, BN=128, BK=64, 512 thr,
// per-wave 128x32 single-mat. 3 rounds/ktile -> vmcnt(3).
__global__ __launch_bounds__(512, 2) void gemm2_kernel(
    const signed char* __restrict__ Aq, const signed char* __restrict__ Bq,
    const float* __restrict__ drow, const float* __restrict__ scalef,
    float* __restrict__ O) {
  const int K = 8192, T = K / 64;
  const int BUF = 24576;  // A 16K | B 8K
  __shared__ __align__(16) signed char smem[3 * BUF];  // 72 KiB
  const int tid = threadIdx.x;
  const int wid = tid >> 6;
  const int lane = tid & 63;
  const int wr = wid >> 2, wn = wid & 3;

  // 256 blocks; XCD x owns N-cols {2x, 2x+1}, all 16 M.
  const int id = blockIdx.x;
  const int xcd = id & 7, j = id >> 3;
  const int mbase = (j & 15) * 256;
  const int nbase = (xcd * 2 + (j >> 4)) * 128;

  const int srow = tid >> 2;
  const int scol = (((tid & 3) ^ ((srow >> 1) & 3)) << 4);
  const signed char* pA = Aq + (size_t)(mbase + srow) * K + scol;
  const signed char* pB = Bq + (size_t)(nbase + srow) * K + scol;

  i32x4 acc[8][2] = {};

  const int kos = (((lane >> 4) ^ ((lane >> 1) & 3)) << 4);
  const int rA = (wr << 7) + (lane & 15);
  const int rB = (wn << 5) + (lane & 15);
  const int wb = wid << 10;

  {
    gload_lds16(pA, &smem[wb]);
    gload_lds16(pA + (size_t)128 * K, &smem[8192 + wb]);
    gload_lds16(pB, &smem[16384 + wb]);
    gload_lds16(pA + 64, &smem[BUF + wb]);
    gload_lds16(pA + (size_t)128 * K + 64, &smem[BUF + 8192 + wb]);
    gload_lds16(pB + 64, &smem[BUF + 16384 + wb]);
  }

  int bc = 0, bn = BUF, bf = 2 * BUF;
  for (int t = 0; t < T; ++t) {
    const size_t kk = (size_t)((t + 2 < T) ? (t + 2) * 64 : (T - 1) * 64);
    S_WAITCNT_VMCNT(3);
    __builtin_amdgcn_s_barrier();
    __builtin_amdgcn_sched_barrier(0);
    // ---- phase 0: a[0..3], b[0..1] -> MFMA m0..3
    i32x4 a[8], b[2];
#pragma unroll
    for (int m = 0; m < 4; ++m)
      a[m] = *(const i32x4*)&smem[bc + (rA + m * 16) * 64 + kos];
#pragma unroll
    for (int n = 0; n < 2; ++n)
      b[n] = *(const i32x4*)&smem[bc + 16384 + (rB + n * 16) * 64 + kos];
    gload_lds16(pA + kk, &smem[bf + wb]);
    gload_lds16(pA + (size_t)128 * K + kk, &smem[bf + 8192 + wb]);
    __builtin_amdgcn_s_barrier();
    S_WAITCNT_LGKM0();
    __builtin_amdgcn_sched_barrier(0);
    __builtin_amdgcn_s_setprio(1);
#pragma unroll
    for (int m = 0; m < 4; ++m)
#pragma unroll
      for (int n = 0; n < 2; ++n)
        acc[m][n] = __builtin_amdgcn_mfma_i32_16x16x64_i8(a[m], b[n], acc[m][n], 0, 0, 0);
    __builtin_amdgcn_s_setprio(0);
    // ---- phase 1: a[4..7] -> MFMA m4..7
#pragma unroll
    for (int m = 4; m < 8; ++m)
      a[m] = *(const i32x4*)&smem[bc + (rA + m * 16) * 64 + kos];
    gload_lds16(pB + kk, &smem[bf + 16384 + wb]);
    __builtin_amdgcn_s_barrier();
    S_WAITCNT_LGKM0();
    __builtin_amdgcn_sched_barrier(0);
    __builtin_amdgcn_s_setprio(1);
#pragma unroll
    for (int m = 4; m < 8; ++m)
#pragma unroll
      for (int n = 0; n < 2; ++n)
        acc[m][n] = __builtin_amdgcn_mfma_i32_16x16x64_i8(a[m], b[n], acc[m][n], 0, 0, 0);
    __builtin_amdgcn_s_setprio(0);
    const int tmp = bc; bc = bn; bn = bf; bf = tmp;
  }

  const float sd = scalef[2];
  const int orow = (lane >> 4) << 2;
  const int ocol = lane & 15;
#pragma unroll
  for (int m = 0; m < 8; ++m)
#pragma unroll
    for (int n = 0; n < 2; ++n)
#pragma unroll
      for (int jj = 0; jj < 4; ++jj) {
        int grow = mbase + (wr << 7) + m * 16 + orow + jj;
        int gcol = nbase + (wn << 5) + n * 16 + ocol;
        O[(size_t)grow * 2048 + gcol] = (float)acc[m][n][jj] * (sd * drow[grow]);
      }
}

// ---------------------------------------------------------------------------
extern "C" void kernel_launch(void* const* d_in, const int* in_sizes, int n_in,
                              void* d_out, int out_size, void* d_ws, size_t ws_size,
                              hipStream_t stream) {
  (void)in_sizes; (void)n_in; (void)out_size; (void)ws_size;
  const float* x = (const float*)d_in[0];
  const float* wg = (const float*)d_in[1];
  const float* wu = (const float*)d_in[2];
  const float* wd = (const float*)d_in[3];
  float* out = (float*)d_out;

  char* ws = (char*)d_ws;
  double* sums = (double*)ws;
  float* scalef = (float*)(ws + 256);
  size_t off = 1024;
  signed char* qg = (signed char*)(ws + off); off += 16777216;
  signed char* qu = (signed char*)(ws + off); off += 16777216;
  signed char* qd = (signed char*)(ws + off); off += 16777216;
  signed char* xq = (signed char*)(ws + off); off += 8388608;
  signed char* hq = (signed char*)(ws + off); off += 33554432;
  float* dr1 = (float*)(ws + off); off += 16384;
  float* dr2 = (float*)(ws + off); off += 16384;
  float* Hbuf = (float*)(ws + off); off += (size_t)4096 * 8192 * 4;

  zero_sums_kernel<<<1, 64, 0, stream>>>(sums);
  absmean_kernel<<<dim3(1024, 3), 256, 0, stream>>>(wg, wu, wd, sums);
  wquant_kernel<<<dim3(16384, 3), 256, 0, stream>>>(wg, wu, wd, qg, qu, qd, sums,
                                                    scalef);
  const float c1 = (float)(1.0 / sqrt(2048.0));
  const float c2 = (float)(1.0 / sqrt(8192.0));
  fwht_quant_kernel<2048><<<4096, 256, 0, stream>>>(x, xq, dr1, c1);
  gemm1_kernel<<<1024, 512, 0, stream>>>(xq, qg, qu, dr1, scalef, Hbuf);
  fwht_quant_kernel<8192><<<4096, 256, 0, stream>>>(Hbuf, hq, dr2, c2);
  gemm2_kernel<<<256, 512, 0, stream>>>(hq, qd, dr2, scalef, out);
}